// Round 1
// baseline (1085.501 us; speedup 1.0000x reference)
//
#include <hip/hip_runtime.h>

// SelfAttentionLayer: B=8, N=2048, D=1024, fp32 in/out.
// Strategy: fp16 MFMA (16x16x32) for all 4 matmuls; fp32 softmax with
// two-pass online stats (no S materialization). ws ~198MB.

typedef _Float16 f16;
typedef _Float16 f16x4 __attribute__((ext_vector_type(4)));
typedef _Float16 f16x8 __attribute__((ext_vector_type(8)));
typedef float f32x4 __attribute__((ext_vector_type(4)));

#define Bb 8
#define Nn_ 2048
#define Dd 1024

// ---------------- fp32 -> fp16 convert ----------------
__global__ void cvt_kernel(const float4* __restrict__ in, f16x4* __restrict__ out, int n4) {
    int i = blockIdx.x * 256 + threadIdx.x;
    if (i >= n4) return;
    float4 f = in[i];
    f16x4 h;
    h.x = (_Float16)f.x; h.y = (_Float16)f.y; h.z = (_Float16)f.z; h.w = (_Float16)f.w;
    out[i] = h;
}

// ---------------- generic BT GEMM ----------------
// C[m,n] = sum_k A[m,k]*Bm[n,k] (+bias[n])
// mode 0: fp16 out, C[m*Nn+n]          (q,k projections)
// mode 1: fp16 out, transposed per batch: C[(m>>11)*Dd*Nn_ + n*Nn_ + (m&2047)]  (v^T)
// mode 2: fp32 out to d_out, C[m*Nn+n], batched via blockIdx.z
__global__ __launch_bounds__(256) void gemm_bt(
    const f16* __restrict__ A, const f16* __restrict__ Bm,
    const float* __restrict__ bias, void* __restrict__ Cout,
    int M, int Nc, int K, int mode,
    long aStride, long bStride, long cStride)
{
    __shared__ f16 As[128 * 32];
    __shared__ f16 Bs[128 * 32];
    const int tid = threadIdx.x;
    const int lane = tid & 63, wid = tid >> 6;
    const int quad = lane >> 4, l16 = lane & 15;
    const int wm = (wid >> 1) * 64, wn = (wid & 1) * 64;
    const long m0 = (long)blockIdx.x * 128, n0 = (long)blockIdx.y * 128;
    const int bz = blockIdx.z;
    A += (long)bz * aStride;
    Bm += (long)bz * bStride;

    const int ca = tid, cb = tid + 256;
    const long ar0 = m0 + (ca >> 2), ar1 = m0 + (cb >> 2);
    const long br0 = n0 + (ca >> 2), br1 = n0 + (cb >> 2);
    const int col0 = (ca & 3) * 8, col1 = (cb & 3) * 8;

    f32x4 acc[4][4];
#pragma unroll
    for (int i = 0; i < 4; i++)
#pragma unroll
        for (int j = 0; j < 4; j++) acc[i][j] = 0.0f;

    for (int k0 = 0; k0 < K; k0 += 32) {
        uint4 va0 = *(const uint4*)(A + ar0 * K + k0 + col0);
        uint4 va1 = *(const uint4*)(A + ar1 * K + k0 + col1);
        uint4 vb0 = *(const uint4*)(Bm + br0 * K + k0 + col0);
        uint4 vb1 = *(const uint4*)(Bm + br1 * K + k0 + col1);
        __syncthreads();
        *(uint4*)(As + ca * 8) = va0;
        *(uint4*)(As + cb * 8) = va1;
        *(uint4*)(Bs + ca * 8) = vb0;
        *(uint4*)(Bs + cb * 8) = vb1;
        __syncthreads();
        f16x8 af[4], bf[4];
#pragma unroll
        for (int rt = 0; rt < 4; rt++)
            af[rt] = *(const f16x8*)(As + (wm + rt * 16 + l16) * 32 + quad * 8);
#pragma unroll
        for (int ct = 0; ct < 4; ct++)
            bf[ct] = *(const f16x8*)(Bs + (wn + ct * 16 + l16) * 32 + quad * 8);
#pragma unroll
        for (int rt = 0; rt < 4; rt++)
#pragma unroll
            for (int ct = 0; ct < 4; ct++)
                acc[rt][ct] = __builtin_amdgcn_mfma_f32_16x16x32_f16(af[rt], bf[ct], acc[rt][ct], 0, 0, 0);
    }

    if (mode == 2) {
        float* O = (float*)Cout + (long)bz * cStride;
#pragma unroll
        for (int ct = 0; ct < 4; ct++) {
            long n = n0 + wn + ct * 16 + l16;
#pragma unroll
            for (int rt = 0; rt < 4; rt++) {
                long mb = m0 + wm + rt * 16 + quad * 4;
#pragma unroll
                for (int r = 0; r < 4; r++)
                    O[(mb + r) * Nc + n] = acc[rt][ct][r];
            }
        }
    } else {
        f16* O = (f16*)Cout;
#pragma unroll
        for (int ct = 0; ct < 4; ct++) {
            long n = n0 + wn + ct * 16 + l16;
            float bs = bias[n];
#pragma unroll
            for (int rt = 0; rt < 4; rt++) {
                long mb = m0 + wm + rt * 16 + quad * 4;
#pragma unroll
                for (int r = 0; r < 4; r++) {
                    float v = acc[rt][ct][r] + bs;
                    long m = mb + r;
                    if (mode == 0)
                        O[m * Nc + n] = (f16)v;
                    else  // v^T: [batch][e][token]
                        O[(m >> 11) * (long)(Dd * Nn_) + n * (long)Nn_ + (m & 2047)] = (f16)v;
                }
            }
        }
    }
}

// ---------------- fused scores+softmax -> P (fp16) ----------------
// Per block: 128 Q rows of one batch. Two passes over 16 column chunks of 128.
// Pass 0: online (m,l) stats per row. Pass 1: recompute S, write P=exp(S-m)/l.
// Wave w owns rows [w*32, w*32+32) exclusively -> stats are wave-local.
__global__ __launch_bounds__(256) void attn_probs(
    const f16* __restrict__ qh, const f16* __restrict__ kh, f16* __restrict__ P)
{
    __shared__ f16 Qs[128 * 32];
    __shared__ f16 Ks[128 * 32];
    const int tid = threadIdx.x;
    const int lane = tid & 63, wid = tid >> 6;
    const int quad = lane >> 4, l16 = lane & 15;
    const int b = blockIdx.y;
    const long m0 = (long)blockIdx.x * 128;
    const f16* Q = qh + (long)b * Nn_ * Dd;
    const f16* Kp = kh + (long)b * Nn_ * Dd;
    f16* Pb = P + (long)b * Nn_ * Nn_;
    const int wr = wid * 32;

    const int ca = tid, cb = tid + 256;
    const int col0 = (ca & 3) * 8, col1 = (cb & 3) * 8;

    float ms[8], ls[8], li[8];
#pragma unroll
    for (int i = 0; i < 8; i++) { ms[i] = -1e30f; ls[i] = 0.0f; li[i] = 0.0f; }

    for (int pass = 0; pass < 2; ++pass) {
        if (pass == 1) {
#pragma unroll
            for (int i = 0; i < 8; i++) li[i] = 1.0f / ls[i];
        }
        for (int c = 0; c < 16; ++c) {
            f32x4 acc[2][8];
#pragma unroll
            for (int i = 0; i < 2; i++)
#pragma unroll
                for (int j = 0; j < 8; j++) acc[i][j] = 0.0f;

            for (int k0 = 0; k0 < Dd; k0 += 32) {
                uint4 va0 = *(const uint4*)(Q + (m0 + (ca >> 2)) * Dd + k0 + col0);
                uint4 va1 = *(const uint4*)(Q + (m0 + (cb >> 2)) * Dd + k0 + col1);
                uint4 vb0 = *(const uint4*)(Kp + ((long)c * 128 + (ca >> 2)) * Dd + k0 + col0);
                uint4 vb1 = *(const uint4*)(Kp + ((long)c * 128 + (cb >> 2)) * Dd + k0 + col1);
                __syncthreads();
                *(uint4*)(Qs + ca * 8) = va0;
                *(uint4*)(Qs + cb * 8) = va1;
                *(uint4*)(Ks + ca * 8) = vb0;
                *(uint4*)(Ks + cb * 8) = vb1;
                __syncthreads();
                f16x8 af0 = *(const f16x8*)(Qs + (wr + l16) * 32 + quad * 8);
                f16x8 af1 = *(const f16x8*)(Qs + (wr + 16 + l16) * 32 + quad * 8);
#pragma unroll
                for (int ct = 0; ct < 8; ++ct) {
                    f16x8 bf = *(const f16x8*)(Ks + (ct * 16 + l16) * 32 + quad * 8);
                    acc[0][ct] = __builtin_amdgcn_mfma_f32_16x16x32_f16(af0, bf, acc[0][ct], 0, 0, 0);
                    acc[1][ct] = __builtin_amdgcn_mfma_f32_16x16x32_f16(af1, bf, acc[1][ct], 0, 0, 0);
                }
            }

            if (pass == 0) {
#pragma unroll
                for (int rt = 0; rt < 2; rt++)
#pragma unroll
                    for (int r = 0; r < 4; r++) {
                        int idx = rt * 4 + r;
                        float mx = acc[rt][0][r];
#pragma unroll
                        for (int ct = 1; ct < 8; ct++) mx = fmaxf(mx, acc[rt][ct][r]);
#pragma unroll
                        for (int off = 1; off < 16; off <<= 1)
                            mx = fmaxf(mx, __shfl_xor(mx, off, 64));
                        float se = 0.0f;
#pragma unroll
                        for (int ct = 0; ct < 8; ct++) se += __expf(acc[rt][ct][r] - mx);
#pragma unroll
                        for (int off = 1; off < 16; off <<= 1)
                            se += __shfl_xor(se, off, 64);
                        float nm = fmaxf(ms[idx], mx);
                        ls[idx] = ls[idx] * __expf(ms[idx] - nm) + se * __expf(mx - nm);
                        ms[idx] = nm;
                    }
            } else {
#pragma unroll
                for (int rt = 0; rt < 2; rt++)
#pragma unroll
                    for (int ct = 0; ct < 8; ct++)
#pragma unroll
                        for (int r = 0; r < 4; r++) {
                            long row = m0 + wr + rt * 16 + quad * 4 + r;
                            float p = __expf(acc[rt][ct][r] - ms[rt * 4 + r]) * li[rt * 4 + r];
                            Pb[row * Nn_ + c * 128 + ct * 16 + l16] = (f16)p;
                        }
            }
        }
    }
}

extern "C" void kernel_launch(void* const* d_in, const int* in_sizes, int n_in,
                              void* d_out, int out_size, void* d_ws, size_t ws_size,
                              hipStream_t stream) {
    const float* x  = (const float*)d_in[0];
    const float* Wq = (const float*)d_in[1];
    const float* bq = (const float*)d_in[2];
    const float* Wk = (const float*)d_in[3];
    const float* bk = (const float*)d_in[4];
    const float* Wv = (const float*)d_in[5];
    const float* bv = (const float*)d_in[6];

    // ws layout (f16 units): xh[16.8M] Wh[3x1M] qh kh vT[each 16.8M] P[33.5M] ~= 198MB
    f16* wsh = (f16*)d_ws;
    f16* xh  = wsh;                       // 16777216
    f16* Wqh = wsh + 16777216;            // 1048576
    f16* Wkh = Wqh + 1048576;
    f16* Wvh = Wkh + 1048576;
    f16* qh  = wsh + 19922944;            // 16777216
    f16* kh  = qh + 16777216;
    f16* vT  = kh + 16777216;             // [b][e][tok]
    f16* P   = vT + 16777216;             // 33554432

    cvt_kernel<<<16384, 256, 0, stream>>>((const float4*)x, (f16x4*)xh, 4194304);
    cvt_kernel<<<1024, 256, 0, stream>>>((const float4*)Wq, (f16x4*)Wqh, 262144);
    cvt_kernel<<<1024, 256, 0, stream>>>((const float4*)Wk, (f16x4*)Wkh, 262144);
    cvt_kernel<<<1024, 256, 0, stream>>>((const float4*)Wv, (f16x4*)Wvh, 262144);

    dim3 blk(256);
    // Q,K,V projections: M=16384, N=1024, K=1024
    gemm_bt<<<dim3(128, 8, 1), blk, 0, stream>>>(xh, Wqh, bq, qh, 16384, 1024, 1024, 0, 0, 0, 0);
    gemm_bt<<<dim3(128, 8, 1), blk, 0, stream>>>(xh, Wkh, bk, kh, 16384, 1024, 1024, 0, 0, 0, 0);
    gemm_bt<<<dim3(128, 8, 1), blk, 0, stream>>>(xh, Wvh, bv, vT, 16384, 1024, 1024, 1, 0, 0, 0);
    // P = softmax(Q K^T)
    attn_probs<<<dim3(16, 8, 1), blk, 0, stream>>>(qh, kh, P);
    // out = P V  (batched; B-operand = vT so K is contiguous)
    gemm_bt<<<dim3(16, 8, 8), blk, 0, stream>>>(P, vT, nullptr, d_out, 2048, 1024, 2048, 2,
        (long)Nn_ * Nn_, (long)Dd * Nn_, (long)Nn_ * Dd);
}

// Round 2
// 599.746 us; speedup vs baseline: 1.8099x; 1.8099x over previous
//
#include <hip/hip_runtime.h>

// SelfAttentionLayer: B=8, N=2048, D=1024, fp32 in/out.
// R2: GEMM-decomposed attention. S=QK^T materialized fp32 (half-batch at a
// time, 67MB buffer), row-softmax writes P fp16 in-place over S, PV GEMM.
// All GEMMs use global_load_lds width-16 staging (m97 pattern).

typedef _Float16 f16;
typedef _Float16 f16x4 __attribute__((ext_vector_type(4)));
typedef _Float16 f16x8 __attribute__((ext_vector_type(8)));
typedef float f32x4 __attribute__((ext_vector_type(4)));

#define Bb 8
#define Nn_ 2048
#define Dd 1024

typedef const __attribute__((address_space(1))) void gvoid;
typedef __attribute__((address_space(3))) void lvoid;

__device__ __forceinline__ void glds16(const void* g, void* l) {
    __builtin_amdgcn_global_load_lds((gvoid*)g, (lvoid*)l, 16, 0, 0);
}

// ---------------- fp32 -> fp16 convert ----------------
__global__ void cvt_kernel(const float4* __restrict__ in, f16x4* __restrict__ out, int n4) {
    int i = blockIdx.x * 256 + threadIdx.x;
    if (i >= n4) return;
    float4 f = in[i];
    f16x4 h;
    h.x = (_Float16)f.x; h.y = (_Float16)f.y; h.z = (_Float16)f.z; h.w = (_Float16)f.w;
    out[i] = h;
}

// ---------------- generic BT GEMM, 128x128 tile, global_load_lds staging ----
// C[m,n] = sum_k A[m,k]*Bm[n,k] (+bias[n])
// mode 0: fp16 out row-major + bias      (q,k projections)
// mode 1: fp16 out transposed per batch + bias: vT[b][e][tok]
// mode 2: fp32 out row-major, no bias    (S-GEMM, PV final output)
__global__ __launch_bounds__(256) void gemm_bt(
    const f16* __restrict__ A, const f16* __restrict__ Bm,
    const float* __restrict__ bias, void* __restrict__ Cout,
    int K, int lda, int ldb, int ldc, int mode,
    long aStride, long bStride, long cStride)
{
    __shared__ f16 As[128 * 32];
    __shared__ f16 Bs[128 * 32];
    const int tid = threadIdx.x;
    const int lane = tid & 63, wid = tid >> 6;
    const int quad = lane >> 4, l16 = lane & 15;
    const int wm = (wid >> 1) * 64, wn = (wid & 1) * 64;
    const long m0 = (long)blockIdx.x * 128, n0 = (long)blockIdx.y * 128;
    const int bz = blockIdx.z;
    A += (long)bz * aStride;
    Bm += (long)bz * bStride;

    const int ca = tid, cb = tid + 256;
    const long ar0 = m0 + (ca >> 2), ar1 = m0 + (cb >> 2);
    const long br0 = n0 + (ca >> 2), br1 = n0 + (cb >> 2);
    const int col0 = (ca & 3) * 8, col1 = (cb & 3) * 8;

    f32x4 acc[4][4];
#pragma unroll
    for (int i = 0; i < 4; i++)
#pragma unroll
        for (int j = 0; j < 4; j++) acc[i][j] = 0.0f;

    for (int k0 = 0; k0 < K; k0 += 32) {
        __syncthreads();   // previous tile fully consumed
        glds16(A + ar0 * lda + k0 + col0, As + ca * 8);
        glds16(A + ar1 * lda + k0 + col1, As + cb * 8);
        glds16(Bm + br0 * ldb + k0 + col0, Bs + ca * 8);
        glds16(Bm + br1 * ldb + k0 + col1, Bs + cb * 8);
        __syncthreads();   // drains vmcnt before barrier
        f16x8 af[4], bf[4];
#pragma unroll
        for (int rt = 0; rt < 4; rt++)
            af[rt] = *(const f16x8*)(As + (wm + rt * 16 + l16) * 32 + quad * 8);
#pragma unroll
        for (int ct = 0; ct < 4; ct++)
            bf[ct] = *(const f16x8*)(Bs + (wn + ct * 16 + l16) * 32 + quad * 8);
#pragma unroll
        for (int rt = 0; rt < 4; rt++)
#pragma unroll
            for (int ct = 0; ct < 4; ct++)
                acc[rt][ct] = __builtin_amdgcn_mfma_f32_16x16x32_f16(af[rt], bf[ct], acc[rt][ct], 0, 0, 0);
    }

    if (mode == 2) {
        float* O = (float*)Cout + (long)bz * cStride;
#pragma unroll
        for (int ct = 0; ct < 4; ct++) {
            long n = n0 + wn + ct * 16 + l16;
#pragma unroll
            for (int rt = 0; rt < 4; rt++) {
                long mb = m0 + wm + rt * 16 + quad * 4;
#pragma unroll
                for (int r = 0; r < 4; r++)
                    O[(mb + r) * ldc + n] = acc[rt][ct][r];
            }
        }
    } else {
        f16* O = (f16*)Cout;
#pragma unroll
        for (int ct = 0; ct < 4; ct++) {
            long n = n0 + wn + ct * 16 + l16;
            float bs = bias[n];
#pragma unroll
            for (int rt = 0; rt < 4; rt++) {
                long mb = m0 + wm + rt * 16 + quad * 4;
#pragma unroll
                for (int r = 0; r < 4; r++) {
                    float v = acc[rt][ct][r] + bs;
                    long m = mb + r;
                    if (mode == 0)
                        O[m * ldc + n] = (f16)v;
                    else  // v^T: [batch][e][token]
                        O[(m >> 11) * (long)(Dd * Nn_) + n * (long)Nn_ + (m & 2047)] = (f16)v;
                }
            }
        }
    }
}

// ---------------- row softmax, P fp16 written in-place over S fp32 --------
// One wave per row of 2048 fp32. Row byte stride 8192; P occupies first 4096B.
__global__ __launch_bounds__(256) void softmax_rows(float* __restrict__ S) {
    const int row = blockIdx.x * 4 + (threadIdx.x >> 6);
    const int lane = threadIdx.x & 63;
    float* Sr = S + (long)row * 2048;
    const float4* R4 = (const float4*)Sr;
    float4 t[8];
#pragma unroll
    for (int i = 0; i < 8; i++) t[i] = R4[lane + 64 * i];
    float mx = -1e30f;
#pragma unroll
    for (int i = 0; i < 8; i++) {
        mx = fmaxf(mx, fmaxf(fmaxf(t[i].x, t[i].y), fmaxf(t[i].z, t[i].w)));
    }
#pragma unroll
    for (int off = 1; off < 64; off <<= 1) mx = fmaxf(mx, __shfl_xor(mx, off, 64));
    float se = 0.0f;
#pragma unroll
    for (int i = 0; i < 8; i++) {
        t[i].x = __expf(t[i].x - mx); t[i].y = __expf(t[i].y - mx);
        t[i].z = __expf(t[i].z - mx); t[i].w = __expf(t[i].w - mx);
        se += t[i].x + t[i].y + t[i].z + t[i].w;
    }
#pragma unroll
    for (int off = 1; off < 64; off <<= 1) se += __shfl_xor(se, off, 64);
    const float li = 1.0f / se;
    f16x4* P4 = (f16x4*)Sr;
#pragma unroll
    for (int i = 0; i < 8; i++) {
        f16x4 h;
        h.x = (_Float16)(t[i].x * li); h.y = (_Float16)(t[i].y * li);
        h.z = (_Float16)(t[i].z * li); h.w = (_Float16)(t[i].w * li);
        P4[lane + 64 * i] = h;
    }
}

extern "C" void kernel_launch(void* const* d_in, const int* in_sizes, int n_in,
                              void* d_out, int out_size, void* d_ws, size_t ws_size,
                              hipStream_t stream) {
    const float* x  = (const float*)d_in[0];
    const float* Wq = (const float*)d_in[1];
    const float* bq = (const float*)d_in[2];
    const float* Wk = (const float*)d_in[3];
    const float* bk = (const float*)d_in[4];
    const float* Wv = (const float*)d_in[5];
    const float* bv = (const float*)d_in[6];

    // ws layout (f16 units): xh[16.8M] Wh[3x1M] qh kh vT[each 16.8M] then
    // S fp32 for 4 batches [4*2048*2048 floats = 67MB]. Total ~207MB.
    f16* wsh = (f16*)d_ws;
    f16* xh  = wsh;                       // 16777216
    f16* Wqh = wsh + 16777216;            // 1048576
    f16* Wkh = Wqh + 1048576;
    f16* Wvh = Wkh + 1048576;
    f16* qh  = wsh + 19922944;            // 16777216
    f16* kh  = qh + 16777216;
    f16* vT  = kh + 16777216;             // [b][e][tok]
    float* S = (float*)(vT + 16777216);   // 16777216 floats (4 batches)

    cvt_kernel<<<16384, 256, 0, stream>>>((const float4*)x, (f16x4*)xh, 4194304);
    cvt_kernel<<<1024, 256, 0, stream>>>((const float4*)Wq, (f16x4*)Wqh, 262144);
    cvt_kernel<<<1024, 256, 0, stream>>>((const float4*)Wk, (f16x4*)Wkh, 262144);
    cvt_kernel<<<1024, 256, 0, stream>>>((const float4*)Wv, (f16x4*)Wvh, 262144);

    dim3 blk(256);
    // Q,K,V projections: M=16384, N=1024, K=1024
    gemm_bt<<<dim3(128, 8, 1), blk, 0, stream>>>(xh, Wqh, bq, qh, 1024, 1024, 1024, 1024, 0, 0, 0, 0);
    gemm_bt<<<dim3(128, 8, 1), blk, 0, stream>>>(xh, Wkh, bk, kh, 1024, 1024, 1024, 1024, 0, 0, 0, 0);
    gemm_bt<<<dim3(128, 8, 1), blk, 0, stream>>>(xh, Wvh, bv, vT, 1024, 1024, 1024, 1024, 1, 0, 0, 0);

    // Attention in two half-batches of 4, reusing the 67MB S buffer.
    for (int h = 0; h < 2; ++h) {
        const long b0 = 4L * h;
        // S = Q K^T : per-batch 2048x2048, K=1024
        gemm_bt<<<dim3(16, 16, 4), blk, 0, stream>>>(
            qh + b0 * Nn_ * Dd, kh + b0 * Nn_ * Dd, nullptr, S,
            1024, 1024, 1024, 2048, 2,
            (long)Nn_ * Dd, (long)Nn_ * Dd, (long)Nn_ * Nn_);
        // softmax rows, P fp16 overlaid in-place (row stride 4096 f16)
        softmax_rows<<<2048, 256, 0, stream>>>(S);
        // out = P V : per-batch 2048x1024, K=2048; A rows strided 4096 f16
        gemm_bt<<<dim3(16, 8, 4), blk, 0, stream>>>(
            (const f16*)S, vT + b0 * Dd * Nn_, nullptr,
            (float*)d_out + b0 * Nn_ * Dd,
            2048, 4096, 2048, 1024, 2,
            (long)Nn_ * 4096, (long)Dd * Nn_, (long)Nn_ * Dd);
    }
}

// Round 3
// 563.782 us; speedup vs baseline: 1.9254x; 1.0638x over previous
//
#include <hip/hip_runtime.h>

// SelfAttentionLayer: B=8, N=2048, D=1024, fp32 in/out.
// R3: merged QKV projection GEMM (N=3072, 3072 blocks); full-8-batch
// S/softmax/PV chain when ws_size allows (S=134MB overlaying dead xh/Wh),
// else two-half fallback. All GEMMs: 128x128 tile, 16x16x32 f16 MFMA,
// global_load_lds width-16 staging (m97 pattern).

typedef _Float16 f16;
typedef _Float16 f16x4 __attribute__((ext_vector_type(4)));
typedef _Float16 f16x8 __attribute__((ext_vector_type(8)));
typedef float f32x4 __attribute__((ext_vector_type(4)));

#define Bb 8
#define Nn_ 2048
#define Dd 1024

typedef const __attribute__((address_space(1))) void gvoid;
typedef __attribute__((address_space(3))) void lvoid;

__device__ __forceinline__ void glds16(const void* g, void* l) {
    __builtin_amdgcn_global_load_lds((gvoid*)g, (lvoid*)l, 16, 0, 0);
}

// ---------------- fp32 -> fp16 convert ----------------
__global__ void cvt_kernel(const float4* __restrict__ in, f16x4* __restrict__ out, int n4) {
    int i = blockIdx.x * 256 + threadIdx.x;
    if (i >= n4) return;
    float4 f = in[i];
    f16x4 h;
    h.x = (_Float16)f.x; h.y = (_Float16)f.y; h.z = (_Float16)f.z; h.w = (_Float16)f.w;
    out[i] = h;
}

// ---------------- bias concat: bqkv[3072] = [bq|bk|bv] ----------------
__global__ void concat_bias(const float* __restrict__ bq, const float* __restrict__ bk,
                            const float* __restrict__ bv, float* __restrict__ o) {
    int i = blockIdx.x * 256 + threadIdx.x;
    if (i >= 3072) return;
    o[i] = (i < 1024) ? bq[i] : (i < 2048 ? bk[i - 1024] : bv[i - 2048]);
}

// ---------------- generic BT GEMM, 128x128 tile, global_load_lds staging ----
// C[m,n] = sum_k A[m,k]*Bm[n,k] (+bias[n])
// mode 2: fp32 out row-major, no bias   (S-GEMM, PV->d_out)
// mode 3: merged QKV epilogue: fp16+bias, n<1024 -> qh, <2048 -> kh,
//         else vT[b][e][tok] transposed per batch.
__global__ __launch_bounds__(256) void gemm_bt(
    const f16* __restrict__ A, const f16* __restrict__ Bm,
    const float* __restrict__ bias, void* __restrict__ Cout,
    f16* __restrict__ qh, f16* __restrict__ kh, f16* __restrict__ vT,
    int K, int lda, int ldb, int ldc, int mode,
    long aStride, long bStride, long cStride)
{
    __shared__ f16 As[128 * 32];
    __shared__ f16 Bs[128 * 32];
    const int tid = threadIdx.x;
    const int lane = tid & 63, wid = tid >> 6;
    const int quad = lane >> 4, l16 = lane & 15;
    const int wm = (wid >> 1) * 64, wn = (wid & 1) * 64;
    const long m0 = (long)blockIdx.x * 128, n0 = (long)blockIdx.y * 128;
    const int bz = blockIdx.z;
    A += (long)bz * aStride;
    Bm += (long)bz * bStride;

    const int ca = tid, cb = tid + 256;
    const long ar0 = m0 + (ca >> 2), ar1 = m0 + (cb >> 2);
    const long br0 = n0 + (ca >> 2), br1 = n0 + (cb >> 2);
    const int col0 = (ca & 3) * 8, col1 = (cb & 3) * 8;

    f32x4 acc[4][4];
#pragma unroll
    for (int i = 0; i < 4; i++)
#pragma unroll
        for (int j = 0; j < 4; j++) acc[i][j] = 0.0f;

    for (int k0 = 0; k0 < K; k0 += 32) {
        __syncthreads();   // previous tile fully consumed
        glds16(A + ar0 * lda + k0 + col0, As + ca * 8);
        glds16(A + ar1 * lda + k0 + col1, As + cb * 8);
        glds16(Bm + br0 * ldb + k0 + col0, Bs + ca * 8);
        glds16(Bm + br1 * ldb + k0 + col1, Bs + cb * 8);
        __syncthreads();   // drains vmcnt before barrier
        f16x8 af[4], bf[4];
#pragma unroll
        for (int rt = 0; rt < 4; rt++)
            af[rt] = *(const f16x8*)(As + (wm + rt * 16 + l16) * 32 + quad * 8);
#pragma unroll
        for (int ct = 0; ct < 4; ct++)
            bf[ct] = *(const f16x8*)(Bs + (wn + ct * 16 + l16) * 32 + quad * 8);
#pragma unroll
        for (int rt = 0; rt < 4; rt++)
#pragma unroll
            for (int ct = 0; ct < 4; ct++)
                acc[rt][ct] = __builtin_amdgcn_mfma_f32_16x16x32_f16(af[rt], bf[ct], acc[rt][ct], 0, 0, 0);
    }

    if (mode == 2) {
        float* O = (float*)Cout + (long)bz * cStride;
#pragma unroll
        for (int ct = 0; ct < 4; ct++) {
            long n = n0 + wn + ct * 16 + l16;
#pragma unroll
            for (int rt = 0; rt < 4; rt++) {
                long mb = m0 + wm + rt * 16 + quad * 4;
#pragma unroll
                for (int r = 0; r < 4; r++)
                    O[(mb + r) * ldc + n] = acc[rt][ct][r];
            }
        }
    } else {  // mode 3: merged QKV routing
#pragma unroll
        for (int ct = 0; ct < 4; ct++) {
            long n = n0 + wn + ct * 16 + l16;
            float bs = bias[n];
            int seg = (int)(n >> 10);
            long n1 = n & 1023;
#pragma unroll
            for (int rt = 0; rt < 4; rt++) {
                long mb = m0 + wm + rt * 16 + quad * 4;
#pragma unroll
                for (int r = 0; r < 4; r++) {
                    float v = acc[rt][ct][r] + bs;
                    long m = mb + r;
                    if (seg == 0)
                        qh[m * 1024 + n1] = (f16)v;
                    else if (seg == 1)
                        kh[m * 1024 + n1] = (f16)v;
                    else
                        vT[(m >> 11) * (long)(Dd * Nn_) + n1 * (long)Nn_ + (m & 2047)] = (f16)v;
                }
            }
        }
    }
}

// ---------------- row softmax, P fp16 written in-place over S fp32 --------
// One wave per row of 2048 fp32 (row stride 2048 floats; P row stride 4096 f16).
__global__ __launch_bounds__(256) void softmax_rows(float* __restrict__ S) {
    const int row = blockIdx.x * 4 + (threadIdx.x >> 6);
    const int lane = threadIdx.x & 63;
    float* Sr = S + (long)row * 2048;
    const float4* R4 = (const float4*)Sr;
    float4 t[8];
#pragma unroll
    for (int i = 0; i < 8; i++) t[i] = R4[lane + 64 * i];
    float mx = -1e30f;
#pragma unroll
    for (int i = 0; i < 8; i++)
        mx = fmaxf(mx, fmaxf(fmaxf(t[i].x, t[i].y), fmaxf(t[i].z, t[i].w)));
#pragma unroll
    for (int off = 1; off < 64; off <<= 1) mx = fmaxf(mx, __shfl_xor(mx, off, 64));
    float se = 0.0f;
#pragma unroll
    for (int i = 0; i < 8; i++) {
        t[i].x = __expf(t[i].x - mx); t[i].y = __expf(t[i].y - mx);
        t[i].z = __expf(t[i].z - mx); t[i].w = __expf(t[i].w - mx);
        se += t[i].x + t[i].y + t[i].z + t[i].w;
    }
#pragma unroll
    for (int off = 1; off < 64; off <<= 1) se += __shfl_xor(se, off, 64);
    const float li = 1.0f / se;
    f16x4* P4 = (f16x4*)Sr;
#pragma unroll
    for (int i = 0; i < 8; i++) {
        f16x4 h;
        h.x = (_Float16)(t[i].x * li); h.y = (_Float16)(t[i].y * li);
        h.z = (_Float16)(t[i].z * li); h.w = (_Float16)(t[i].w * li);
        P4[lane + 64 * i] = h;
    }
}

extern "C" void kernel_launch(void* const* d_in, const int* in_sizes, int n_in,
                              void* d_out, int out_size, void* d_ws, size_t ws_size,
                              hipStream_t stream) {
    const float* x  = (const float*)d_in[0];
    const float* Wq = (const float*)d_in[1];
    const float* bq = (const float*)d_in[2];
    const float* Wk = (const float*)d_in[3];
    const float* bk = (const float*)d_in[4];
    const float* Wv = (const float*)d_in[5];
    const float* bv = (const float*)d_in[6];

    f16* wsh = (f16*)d_ws;
    dim3 blk(256);
    const bool full = ws_size >= 234881024ULL;  // 224 MiB full-batch path

    if (full) {
        // layout (f16 elems): qh@0, kh@16777216, vT@33554432, S(fp32)@50331648
        // (S spans 67108864 f16-equiv = 134MB); xh/Wh/bias overlaid inside S
        // region (dead before S-GEMM writes).
        f16* qh  = wsh;
        f16* kh  = wsh + 16777216;
        f16* vT  = wsh + 33554432;
        float* S = (float*)(wsh + 50331648);        // 33554432 floats
        f16* xh  = wsh + 50331648;                  // 16777216 (inside S)
        f16* Wh  = wsh + 67108864;                  // 3145728  (inside S)
        float* bqkv = (float*)(wsh + 70254592);     // 3072 floats (inside S)

        cvt_kernel<<<16384, 256, 0, stream>>>((const float4*)x, (f16x4*)xh, 4194304);
        cvt_kernel<<<1024, 256, 0, stream>>>((const float4*)Wq, (f16x4*)Wh, 262144);
        cvt_kernel<<<1024, 256, 0, stream>>>((const float4*)Wk, (f16x4*)(Wh + 1048576), 262144);
        cvt_kernel<<<1024, 256, 0, stream>>>((const float4*)Wv, (f16x4*)(Wh + 2097152), 262144);
        concat_bias<<<12, 256, 0, stream>>>(bq, bk, bv, bqkv);

        // merged QKV: M=16384, N=3072, K=1024  (3072 blocks)
        gemm_bt<<<dim3(128, 24, 1), blk, 0, stream>>>(
            xh, Wh, bqkv, nullptr, qh, kh, vT,
            1024, 1024, 1024, 0, 3, 0, 0, 0);
        // S = Q K^T : all 8 batches (2048 blocks)
        gemm_bt<<<dim3(16, 16, 8), blk, 0, stream>>>(
            qh, kh, nullptr, S, nullptr, nullptr, nullptr,
            1024, 1024, 1024, 2048, 2,
            (long)Nn_ * Dd, (long)Nn_ * Dd, (long)Nn_ * Nn_);
        softmax_rows<<<4096, 256, 0, stream>>>(S);
        // out = P V : all 8 batches (1024 blocks); P lda=4096 f16 over S
        gemm_bt<<<dim3(16, 8, 8), blk, 0, stream>>>(
            (const f16*)S, vT, nullptr, d_out, nullptr, nullptr, nullptr,
            2048, 4096, 2048, 1024, 2,
            (long)Nn_ * 4096, (long)Dd * Nn_, (long)Nn_ * Dd);
    } else {
        // fallback: proven two-half layout (~198 MiB)
        f16* xh  = wsh;                             // 16777216
        f16* Wh  = wsh + 16777216;                  // 3145728
        float* bqkv = (float*)(wsh + 19922944);     // 3072 floats (6144 f16)
        f16* qh  = wsh + 19929088;
        f16* kh  = qh + 16777216;
        f16* vT  = kh + 16777216;
        float* S = (float*)(vT + 16777216);         // 16777216 floats

        cvt_kernel<<<16384, 256, 0, stream>>>((const float4*)x, (f16x4*)xh, 4194304);
        cvt_kernel<<<1024, 256, 0, stream>>>((const float4*)Wq, (f16x4*)Wh, 262144);
        cvt_kernel<<<1024, 256, 0, stream>>>((const float4*)Wk, (f16x4*)(Wh + 1048576), 262144);
        cvt_kernel<<<1024, 256, 0, stream>>>((const float4*)Wv, (f16x4*)(Wh + 2097152), 262144);
        concat_bias<<<12, 256, 0, stream>>>(bq, bk, bv, bqkv);

        gemm_bt<<<dim3(128, 24, 1), blk, 0, stream>>>(
            xh, Wh, bqkv, nullptr, qh, kh, vT,
            1024, 1024, 1024, 0, 3, 0, 0, 0);

        for (int h = 0; h < 2; ++h) {
            const long b0 = 4L * h;
            gemm_bt<<<dim3(16, 16, 4), blk, 0, stream>>>(
                qh + b0 * Nn_ * Dd, kh + b0 * Nn_ * Dd, nullptr, S,
                nullptr, nullptr, nullptr,
                1024, 1024, 1024, 2048, 2,
                (long)Nn_ * Dd, (long)Nn_ * Dd, (long)Nn_ * Nn_);
            softmax_rows<<<2048, 256, 0, stream>>>(S);
            gemm_bt<<<dim3(16, 8, 4), blk, 0, stream>>>(
                (const f16*)S, vT + b0 * Dd * Nn_, nullptr,
                (float*)d_out + b0 * Nn_ * Dd, nullptr, nullptr, nullptr,
                2048, 4096, 2048, 1024, 2,
                (long)Nn_ * 4096, (long)Dd * Nn_, (long)Nn_ * Dd);
        }
    }
}

// Round 4
// 490.364 us; speedup vs baseline: 2.2137x; 1.1497x over previous
//
#include <hip/hip_runtime.h>

// SelfAttentionLayer: B=8, N=2048, D=1024, fp32 in/out.
// R4: double-buffered LDS K-loop (cross-barrier global_load_lds prefetch,
// ONE barrier/iter) in all GEMMs; coalesced vT epilogue via LDS transpose.
// Pipeline: cvt -> merged QKV GEMM -> S=QK^T (fp32, 134MB) -> row softmax
// (P fp16 in-place) -> PV GEMM -> d_out.

typedef _Float16 f16;
typedef _Float16 f16x4 __attribute__((ext_vector_type(4)));
typedef _Float16 f16x8 __attribute__((ext_vector_type(8)));
typedef float f32x4 __attribute__((ext_vector_type(4)));

#define Nn_ 2048
#define Dd 1024

typedef const __attribute__((address_space(1))) void gvoid;
typedef __attribute__((address_space(3))) void lvoid;

__device__ __forceinline__ void glds16(const void* g, void* l) {
    __builtin_amdgcn_global_load_lds((gvoid*)g, (lvoid*)l, 16, 0, 0);
}

// ---------------- fp32 -> fp16 convert ----------------
__global__ void cvt_kernel(const float4* __restrict__ in, f16x4* __restrict__ out, int n4) {
    int i = blockIdx.x * 256 + threadIdx.x;
    if (i >= n4) return;
    float4 f = in[i];
    f16x4 h;
    h.x = (_Float16)f.x; h.y = (_Float16)f.y; h.z = (_Float16)f.z; h.w = (_Float16)f.w;
    out[i] = h;
}

// ---------------- bias concat: bqkv[3072] = [bq|bk|bv] ----------------
__global__ void concat_bias(const float* __restrict__ bq, const float* __restrict__ bk,
                            const float* __restrict__ bv, float* __restrict__ o) {
    int i = blockIdx.x * 256 + threadIdx.x;
    if (i >= 3072) return;
    o[i] = (i < 1024) ? bq[i] : (i < 2048 ? bk[i - 1024] : bv[i - 2048]);
}

// ---------------- generic BT GEMM, 128x128 tile, dbuf LDS staging ----------
// C[m,n] = sum_k A[m,k]*Bm[n,k] (+bias[n])
// mode 2: fp32 out row-major, no bias       (S-GEMM, PV->d_out)
// mode 3: merged QKV: y<8 -> qh row-major, y<16 -> kh row-major,
//         else vT[b][e][tok] via LDS-transposed coalesced stores.
__global__ __launch_bounds__(256) void gemm_bt(
    const f16* __restrict__ A, const f16* __restrict__ Bm,
    const float* __restrict__ bias, void* __restrict__ Cout,
    f16* __restrict__ qh, f16* __restrict__ kh, f16* __restrict__ vT,
    int K, int lda, int ldb, int ldc, int mode,
    long aStride, long bStride, long cStride)
{
    __shared__ f16 sm[16384];   // 32KB: two 16KB buffers (A 8KB + B 8KB each)
    const int tid = threadIdx.x;
    const int lane = tid & 63, wid = tid >> 6;
    const int quad = lane >> 4, l16 = lane & 15;
    const int wm = (wid >> 1) * 64, wn = (wid & 1) * 64;
    const long m0 = (long)blockIdx.x * 128, n0 = (long)blockIdx.y * 128;
    const int bz = blockIdx.z;
    A += (long)bz * aStride;
    Bm += (long)bz * bStride;

    const int ca = tid, cb = tid + 256;
    const long ar0 = m0 + (ca >> 2), ar1 = m0 + (cb >> 2);
    const long br0 = n0 + (ca >> 2), br1 = n0 + (cb >> 2);
    const int col0 = (ca & 3) * 8, col1 = (cb & 3) * 8;

    const f16* pa0 = A + ar0 * lda + col0;
    const f16* pa1 = A + ar1 * lda + col1;
    const f16* pb0 = Bm + br0 * ldb + col0;
    const f16* pb1 = Bm + br1 * ldb + col1;

    f32x4 acc[4][4];
#pragma unroll
    for (int i = 0; i < 4; i++)
#pragma unroll
        for (int j = 0; j < 4; j++) acc[i][j] = 0.0f;

    // prologue: stage tile 0 into buffer 0
    glds16(pa0, sm + ca * 8);
    glds16(pa1, sm + cb * 8);
    glds16(pb0, sm + 4096 + ca * 8);
    glds16(pb1, sm + 4096 + cb * 8);

    int cur = 0;
    for (int k0 = 0; k0 < K; k0 += 32) {
        __syncthreads();             // drains own vmcnt -> buf[cur] complete
        if (k0 + 32 < K) {           // prefetch next tile into alt buffer
            f16* dst = sm + ((cur ^ 1) << 13);
            glds16(pa0 + k0 + 32, dst + ca * 8);
            glds16(pa1 + k0 + 32, dst + cb * 8);
            glds16(pb0 + k0 + 32, dst + 4096 + ca * 8);
            glds16(pb1 + k0 + 32, dst + 4096 + cb * 8);
        }
        const f16* As = sm + (cur << 13);
        const f16* Bs = As + 4096;
        f16x8 af[4], bf[4];
#pragma unroll
        for (int rt = 0; rt < 4; rt++)
            af[rt] = *(const f16x8*)(As + (wm + rt * 16 + l16) * 32 + quad * 8);
#pragma unroll
        for (int ct = 0; ct < 4; ct++)
            bf[ct] = *(const f16x8*)(Bs + (wn + ct * 16 + l16) * 32 + quad * 8);
#pragma unroll
        for (int rt = 0; rt < 4; rt++)
#pragma unroll
            for (int ct = 0; ct < 4; ct++)
                acc[rt][ct] = __builtin_amdgcn_mfma_f32_16x16x32_f16(af[rt], bf[ct], acc[rt][ct], 0, 0, 0);
        cur ^= 1;
    }

    if (mode == 2) {
        float* O = (float*)Cout + (long)bz * cStride;
#pragma unroll
        for (int ct = 0; ct < 4; ct++) {
            long n = n0 + wn + ct * 16 + l16;
#pragma unroll
            for (int rt = 0; rt < 4; rt++) {
                long mb = m0 + wm + rt * 16 + quad * 4;
#pragma unroll
                for (int r = 0; r < 4; r++)
                    O[(mb + r) * ldc + n] = acc[rt][ct][r];
            }
        }
    } else {  // mode 3: merged QKV routing
        if (blockIdx.y < 16) {
            f16* O = (blockIdx.y < 8) ? qh : kh;
#pragma unroll
            for (int ct = 0; ct < 4; ct++) {
                long n = n0 + wn + ct * 16 + l16;
                float bs = bias[n];
                long n1 = n & 1023;
#pragma unroll
                for (int rt = 0; rt < 4; rt++) {
                    long mb = m0 + wm + rt * 16 + quad * 4;
#pragma unroll
                    for (int r = 0; r < 4; r++)
                        O[(mb + r) * 1024 + n1] = (f16)(acc[rt][ct][r] + bs);
                }
            }
        } else {
            // V: transpose 128m x 128n tile through LDS in two 64-col halves;
            // write vT[b][e][tok] with contiguous 256B rows.
            const long nb = n0 - 2048;
            const long vbase = (m0 >> 11) * (long)(Dd * Nn_) + (m0 & 2047);
#pragma unroll
            for (int h = 0; h < 2; ++h) {
                __syncthreads();     // LDS free (k-loop reads / prev half done)
                if ((wid & 1) == h) {
#pragma unroll
                    for (int ct = 0; ct < 4; ++ct) {
                        int cl = ct * 16 + l16;                 // 0..63
                        float bs = bias[n0 + h * 64 + cl];
#pragma unroll
                        for (int rt = 0; rt < 4; rt++) {
                            int row = wm + rt * 16 + quad * 4;  // + r
#pragma unroll
                            for (int r = 0; r < 4; r++)
                                sm[cl * 136 + row + r] = (f16)(acc[rt][ct][r] + bs);
                        }
                    }
                }
                __syncthreads();
                const int rowi = tid >> 2, c4 = (tid & 3) * 32;
                f16* dst = vT + vbase + (nb + h * 64 + rowi) * (long)Nn_ + c4;
                const f16* src = sm + rowi * 136 + c4;
#pragma unroll
                for (int j = 0; j < 4; ++j)
                    *(f16x8*)(dst + j * 8) = *(const f16x8*)(src + j * 8);
            }
        }
    }
}

// ---------------- row softmax, P fp16 written in-place over S fp32 --------
__global__ __launch_bounds__(256) void softmax_rows(float* __restrict__ S) {
    const int row = blockIdx.x * 4 + (threadIdx.x >> 6);
    const int lane = threadIdx.x & 63;
    float* Sr = S + (long)row * 2048;
    const float4* R4 = (const float4*)Sr;
    float4 t[8];
#pragma unroll
    for (int i = 0; i < 8; i++) t[i] = R4[lane + 64 * i];
    float mx = -1e30f;
#pragma unroll
    for (int i = 0; i < 8; i++)
        mx = fmaxf(mx, fmaxf(fmaxf(t[i].x, t[i].y), fmaxf(t[i].z, t[i].w)));
#pragma unroll
    for (int off = 1; off < 64; off <<= 1) mx = fmaxf(mx, __shfl_xor(mx, off, 64));
    float se = 0.0f;
#pragma unroll
    for (int i = 0; i < 8; i++) {
        t[i].x = __expf(t[i].x - mx); t[i].y = __expf(t[i].y - mx);
        t[i].z = __expf(t[i].z - mx); t[i].w = __expf(t[i].w - mx);
        se += t[i].x + t[i].y + t[i].z + t[i].w;
    }
#pragma unroll
    for (int off = 1; off < 64; off <<= 1) se += __shfl_xor(se, off, 64);
    const float li = 1.0f / se;
    f16x4* P4 = (f16x4*)Sr;
#pragma unroll
    for (int i = 0; i < 8; i++) {
        f16x4 h;
        h.x = (_Float16)(t[i].x * li); h.y = (_Float16)(t[i].y * li);
        h.z = (_Float16)(t[i].z * li); h.w = (_Float16)(t[i].w * li);
        P4[lane + 64 * i] = h;
    }
}

extern "C" void kernel_launch(void* const* d_in, const int* in_sizes, int n_in,
                              void* d_out, int out_size, void* d_ws, size_t ws_size,
                              hipStream_t stream) {
    const float* x  = (const float*)d_in[0];
    const float* Wq = (const float*)d_in[1];
    const float* bq = (const float*)d_in[2];
    const float* Wk = (const float*)d_in[3];
    const float* bk = (const float*)d_in[4];
    const float* Wv = (const float*)d_in[5];
    const float* bv = (const float*)d_in[6];

    f16* wsh = (f16*)d_ws;
    dim3 blk(256);
    const bool full = ws_size >= 234881024ULL;  // 224 MiB full-batch path

    if (full) {
        f16* qh  = wsh;
        f16* kh  = wsh + 16777216;
        f16* vT  = wsh + 33554432;
        float* S = (float*)(wsh + 50331648);        // 33554432 floats
        f16* xh  = wsh + 50331648;                  // overlaid in S (dead later)
        f16* Wh  = wsh + 67108864;
        float* bqkv = (float*)(wsh + 70254592);

        cvt_kernel<<<16384, 256, 0, stream>>>((const float4*)x, (f16x4*)xh, 4194304);
        cvt_kernel<<<1024, 256, 0, stream>>>((const float4*)Wq, (f16x4*)Wh, 262144);
        cvt_kernel<<<1024, 256, 0, stream>>>((const float4*)Wk, (f16x4*)(Wh + 1048576), 262144);
        cvt_kernel<<<1024, 256, 0, stream>>>((const float4*)Wv, (f16x4*)(Wh + 2097152), 262144);
        concat_bias<<<12, 256, 0, stream>>>(bq, bk, bv, bqkv);

        gemm_bt<<<dim3(128, 24, 1), blk, 0, stream>>>(
            xh, Wh, bqkv, nullptr, qh, kh, vT,
            1024, 1024, 1024, 0, 3, 0, 0, 0);
        gemm_bt<<<dim3(16, 16, 8), blk, 0, stream>>>(
            qh, kh, nullptr, S, nullptr, nullptr, nullptr,
            1024, 1024, 1024, 2048, 2,
            (long)Nn_ * Dd, (long)Nn_ * Dd, (long)Nn_ * Nn_);
        softmax_rows<<<4096, 256, 0, stream>>>(S);
        gemm_bt<<<dim3(16, 8, 8), blk, 0, stream>>>(
            (const f16*)S, vT, nullptr, d_out, nullptr, nullptr, nullptr,
            2048, 4096, 2048, 1024, 2,
            (long)Nn_ * 4096, (long)Dd * Nn_, (long)Nn_ * Dd);
    } else {
        f16* xh  = wsh;
        f16* Wh  = wsh + 16777216;
        float* bqkv = (float*)(wsh + 19922944);
        f16* qh  = wsh + 19929088;
        f16* kh  = qh + 16777216;
        f16* vT  = kh + 16777216;
        float* S = (float*)(vT + 16777216);

        cvt_kernel<<<16384, 256, 0, stream>>>((const float4*)x, (f16x4*)xh, 4194304);
        cvt_kernel<<<1024, 256, 0, stream>>>((const float4*)Wq, (f16x4*)Wh, 262144);
        cvt_kernel<<<1024, 256, 0, stream>>>((const float4*)Wk, (f16x4*)(Wh + 1048576), 262144);
        cvt_kernel<<<1024, 256, 0, stream>>>((const float4*)Wv, (f16x4*)(Wh + 2097152), 262144);
        concat_bias<<<12, 256, 0, stream>>>(bq, bk, bv, bqkv);

        gemm_bt<<<dim3(128, 24, 1), blk, 0, stream>>>(
            xh, Wh, bqkv, nullptr, qh, kh, vT,
            1024, 1024, 1024, 0, 3, 0, 0, 0);

        for (int h = 0; h < 2; ++h) {
            const long b0 = 4L * h;
            gemm_bt<<<dim3(16, 16, 4), blk, 0, stream>>>(
                qh + b0 * Nn_ * Dd, kh + b0 * Nn_ * Dd, nullptr, S,
                nullptr, nullptr, nullptr,
                1024, 1024, 1024, 2048, 2,
                (long)Nn_ * Dd, (long)Nn_ * Dd, (long)Nn_ * Nn_);
            softmax_rows<<<2048, 256, 0, stream>>>(S);
            gemm_bt<<<dim3(16, 8, 4), blk, 0, stream>>>(
                (const f16*)S, vT + b0 * Dd * Nn_, nullptr,
                (float*)d_out + b0 * Nn_ * Dd, nullptr, nullptr, nullptr,
                2048, 4096, 2048, 1024, 2,
                (long)Nn_ * 4096, (long)Dd * Nn_, (long)Nn_ * Dd);
        }
    }
}

// Round 5
// 460.574 us; speedup vs baseline: 2.3568x; 1.0647x over previous
//
#include <hip/hip_runtime.h>

// SelfAttentionLayer: B=8, N=2048, D=1024, fp32 in/out.
// R5: (a) XOR-swizzled LDS tile layout -> conflict-free MFMA fragment reads
// (2-way only, free); (b) depth-2 global_load_lds pipeline (3 LDS buffers,
// manual `s_waitcnt vmcnt(4); s_barrier` so prefetch stays in flight across
// the barrier). Pipeline: cvt -> merged QKV GEMM -> S=QK^T fp32 -> row
// softmax (P fp16 in-place) -> PV GEMM.

typedef _Float16 f16;
typedef _Float16 f16x4 __attribute__((ext_vector_type(4)));
typedef _Float16 f16x8 __attribute__((ext_vector_type(8)));
typedef float f32x4 __attribute__((ext_vector_type(4)));

#define Nn_ 2048
#define Dd 1024

typedef const __attribute__((address_space(1))) void gvoid;
typedef __attribute__((address_space(3))) void lvoid;

__device__ __forceinline__ void glds16(const void* g, void* l) {
    __builtin_amdgcn_global_load_lds((gvoid*)g, (lvoid*)l, 16, 0, 0);
}
// barrier with tile-(k+1) loads (4/thread) still in flight
__device__ __forceinline__ void bar_vm4() {
    asm volatile("s_waitcnt vmcnt(4)\n\ts_barrier" ::: "memory");
}
__device__ __forceinline__ void bar_vm0() {
    asm volatile("s_waitcnt vmcnt(0)\n\ts_barrier" ::: "memory");
}

// ---------------- fp32 -> fp16 convert ----------------
__global__ void cvt_kernel(const float4* __restrict__ in, f16x4* __restrict__ out, int n4) {
    int i = blockIdx.x * 256 + threadIdx.x;
    if (i >= n4) return;
    float4 f = in[i];
    f16x4 h;
    h.x = (_Float16)f.x; h.y = (_Float16)f.y; h.z = (_Float16)f.z; h.w = (_Float16)f.w;
    out[i] = h;
}

// ---------------- bias concat: bqkv[3072] = [bq|bk|bv] ----------------
__global__ void concat_bias(const float* __restrict__ bq, const float* __restrict__ bk,
                            const float* __restrict__ bv, float* __restrict__ o) {
    int i = blockIdx.x * 256 + threadIdx.x;
    if (i >= 3072) return;
    o[i] = (i < 1024) ? bq[i] : (i < 2048 ? bk[i - 1024] : bv[i - 2048]);
}

// ---------------- generic BT GEMM, 128x128 tile -----------------------------
// LDS tile layout: row r (0..127, 32 f16) stored as 4 chunks of 8 f16;
// logical chunk q lives at physical chunk q ^ ((r>>1)&3)  (bank swizzle).
// Staged via global_load_lds: lds dst stays base+lane*16B; the SOURCE column
// is permuted per-lane to land the swizzle.
// mode 2: fp32 out row-major, no bias       (S-GEMM, PV->d_out)
// mode 3: merged QKV: y<8 -> qh, y<16 -> kh, else vT via LDS transpose.
__global__ __launch_bounds__(256) void gemm_bt(
    const f16* __restrict__ A, const f16* __restrict__ Bm,
    const float* __restrict__ bias, void* __restrict__ Cout,
    f16* __restrict__ qh, f16* __restrict__ kh, f16* __restrict__ vT,
    int K, int lda, int ldb, int ldc, int mode,
    long aStride, long bStride, long cStride)
{
    __shared__ f16 sm[24576];   // 48KB: three 16KB stages (A 8KB + B 8KB)
    const int tid = threadIdx.x;
    const int lane = tid & 63, wid = tid >> 6;
    const int quad = lane >> 4, l16 = lane & 15;
    const int wm = (wid >> 1) * 64, wn = (wid & 1) * 64;
    const long m0 = (long)blockIdx.x * 128, n0 = (long)blockIdx.y * 128;
    const int bz = blockIdx.z;
    A += (long)bz * aStride;
    Bm += (long)bz * bStride;

    const int ca = tid, cb = tid + 256;
    const long ar0 = m0 + (ca >> 2), ar1 = m0 + (cb >> 2);
    const long br0 = n0 + (ca >> 2), br1 = n0 + (cb >> 2);
    // swizzled source chunk: q = p ^ ((row>>1)&3), p = ca&3, row = ca>>2
    const int col0 = ((ca & 3) ^ ((ca >> 3) & 3)) * 8;
    const int col1 = ((cb & 3) ^ ((cb >> 3) & 3)) * 8;

    const f16* pa0 = A + ar0 * lda + col0;
    const f16* pa1 = A + ar1 * lda + col1;
    const f16* pb0 = Bm + br0 * ldb + col0;
    const f16* pb1 = Bm + br1 * ldb + col1;

    // fragment-read physical chunk offset (loop-invariant):
    const int fo = (quad ^ ((l16 >> 1) & 3)) * 8;

    f32x4 acc[4][4];
#pragma unroll
    for (int i = 0; i < 4; i++)
#pragma unroll
        for (int j = 0; j < 4; j++) acc[i][j] = 0.0f;

    const int nk = K >> 5;
    // prologue: stage tiles 0 and 1
    glds16(pa0, sm + ca * 8);
    glds16(pa1, sm + cb * 8);
    glds16(pb0, sm + 4096 + ca * 8);
    glds16(pb1, sm + 4096 + cb * 8);
    if (nk > 1) {
        glds16(pa0 + 32, sm + 8192 + ca * 8);
        glds16(pa1 + 32, sm + 8192 + cb * 8);
        glds16(pb0 + 32, sm + 12288 + ca * 8);
        glds16(pb1 + 32, sm + 12288 + cb * 8);
    }

    int cur = 0;
    for (int it = 0; it < nk; ++it) {
        if (it + 1 < nk) bar_vm4(); else bar_vm0();
        if (it + 2 < nk) {
            f16* dst = sm + ((cur >= 1) ? (cur - 1) : (cur + 2)) * 8192;  // (cur+2)%3
            const int ko = (it + 2) * 32;
            glds16(pa0 + ko, dst + ca * 8);
            glds16(pa1 + ko, dst + cb * 8);
            glds16(pb0 + ko, dst + 4096 + ca * 8);
            glds16(pb1 + ko, dst + 4096 + cb * 8);
        }
        const f16* As = sm + cur * 8192;
        const f16* Bs = As + 4096;
        f16x8 af[4], bf[4];
#pragma unroll
        for (int rt = 0; rt < 4; rt++)
            af[rt] = *(const f16x8*)(As + (wm + rt * 16 + l16) * 32 + fo);
#pragma unroll
        for (int ct = 0; ct < 4; ct++)
            bf[ct] = *(const f16x8*)(Bs + (wn + ct * 16 + l16) * 32 + fo);
#pragma unroll
        for (int rt = 0; rt < 4; rt++)
#pragma unroll
            for (int ct = 0; ct < 4; ct++)
                acc[rt][ct] = __builtin_amdgcn_mfma_f32_16x16x32_f16(af[rt], bf[ct], acc[rt][ct], 0, 0, 0);
        cur = (cur == 2) ? 0 : cur + 1;
    }

    if (mode == 2) {
        float* O = (float*)Cout + (long)bz * cStride;
#pragma unroll
        for (int ct = 0; ct < 4; ct++) {
            long n = n0 + wn + ct * 16 + l16;
#pragma unroll
            for (int rt = 0; rt < 4; rt++) {
                long mb = m0 + wm + rt * 16 + quad * 4;
#pragma unroll
                for (int r = 0; r < 4; r++)
                    O[(mb + r) * ldc + n] = acc[rt][ct][r];
            }
        }
    } else {  // mode 3: merged QKV routing
        if (blockIdx.y < 16) {
            f16* O = (blockIdx.y < 8) ? qh : kh;
#pragma unroll
            for (int ct = 0; ct < 4; ct++) {
                long n = n0 + wn + ct * 16 + l16;
                float bs = bias[n];
                long n1 = n & 1023;
#pragma unroll
                for (int rt = 0; rt < 4; rt++) {
                    long mb = m0 + wm + rt * 16 + quad * 4;
#pragma unroll
                    for (int r = 0; r < 4; r++)
                        O[(mb + r) * 1024 + n1] = (f16)(acc[rt][ct][r] + bs);
                }
            }
        } else {
            // V: transpose 128m x 128n tile through LDS in two 64-col halves;
            // write vT[b][e][tok] with contiguous 256B rows.
            const long nb = n0 - 2048;
            const long vbase = (m0 >> 11) * (long)(Dd * Nn_) + (m0 & 2047);
#pragma unroll
            for (int h = 0; h < 2; ++h) {
                __syncthreads();     // LDS free (k-loop reads / prev half done)
                if ((wid & 1) == h) {
#pragma unroll
                    for (int ct = 0; ct < 4; ++ct) {
                        int cl = ct * 16 + l16;                 // 0..63
                        float bs = bias[n0 + h * 64 + cl];
#pragma unroll
                        for (int rt = 0; rt < 4; rt++) {
                            int row = wm + rt * 16 + quad * 4;  // + r
#pragma unroll
                            for (int r = 0; r < 4; r++)
                                sm[cl * 136 + row + r] = (f16)(acc[rt][ct][r] + bs);
                        }
                    }
                }
                __syncthreads();
                const int rowi = tid >> 2, c4 = (tid & 3) * 32;
                f16* dst = vT + vbase + (nb + h * 64 + rowi) * (long)Nn_ + c4;
                const f16* src = sm + rowi * 136 + c4;
#pragma unroll
                for (int j = 0; j < 4; ++j)
                    *(f16x8*)(dst + j * 8) = *(const f16x8*)(src + j * 8);
            }
        }
    }
}

// ---------------- row softmax, P fp16 written in-place over S fp32 --------
__global__ __launch_bounds__(256) void softmax_rows(float* __restrict__ S) {
    const int row = blockIdx.x * 4 + (threadIdx.x >> 6);
    const int lane = threadIdx.x & 63;
    float* Sr = S + (long)row * 2048;
    const float4* R4 = (const float4*)Sr;
    float4 t[8];
#pragma unroll
    for (int i = 0; i < 8; i++) t[i] = R4[lane + 64 * i];
    float mx = -1e30f;
#pragma unroll
    for (int i = 0; i < 8; i++)
        mx = fmaxf(mx, fmaxf(fmaxf(t[i].x, t[i].y), fmaxf(t[i].z, t[i].w)));
#pragma unroll
    for (int off = 1; off < 64; off <<= 1) mx = fmaxf(mx, __shfl_xor(mx, off, 64));
    float se = 0.0f;
#pragma unroll
    for (int i = 0; i < 8; i++) {
        t[i].x = __expf(t[i].x - mx); t[i].y = __expf(t[i].y - mx);
        t[i].z = __expf(t[i].z - mx); t[i].w = __expf(t[i].w - mx);
        se += t[i].x + t[i].y + t[i].z + t[i].w;
    }
#pragma unroll
    for (int off = 1; off < 64; off <<= 1) se += __shfl_xor(se, off, 64);
    const float li = 1.0f / se;
    f16x4* P4 = (f16x4*)Sr;
#pragma unroll
    for (int i = 0; i < 8; i++) {
        f16x4 h;
        h.x = (_Float16)(t[i].x * li); h.y = (_Float16)(t[i].y * li);
        h.z = (_Float16)(t[i].z * li); h.w = (_Float16)(t[i].w * li);
        P4[lane + 64 * i] = h;
    }
}

extern "C" void kernel_launch(void* const* d_in, const int* in_sizes, int n_in,
                              void* d_out, int out_size, void* d_ws, size_t ws_size,
                              hipStream_t stream) {
    const float* x  = (const float*)d_in[0];
    const float* Wq = (const float*)d_in[1];
    const float* bq = (const float*)d_in[2];
    const float* Wk = (const float*)d_in[3];
    const float* bk = (const float*)d_in[4];
    const float* Wv = (const float*)d_in[5];
    const float* bv = (const float*)d_in[6];

    f16* wsh = (f16*)d_ws;
    dim3 blk(256);
    const bool full = ws_size >= 234881024ULL;  // 224 MiB full-batch path

    if (full) {
        f16* qh  = wsh;
        f16* kh  = wsh + 16777216;
        f16* vT  = wsh + 33554432;
        float* S = (float*)(wsh + 50331648);        // 33554432 floats
        f16* xh  = wsh + 50331648;                  // overlaid in S (dead later)
        f16* Wh  = wsh + 67108864;
        float* bqkv = (float*)(wsh + 70254592);

        cvt_kernel<<<16384, 256, 0, stream>>>((const float4*)x, (f16x4*)xh, 4194304);
        cvt_kernel<<<1024, 256, 0, stream>>>((const float4*)Wq, (f16x4*)Wh, 262144);
        cvt_kernel<<<1024, 256, 0, stream>>>((const float4*)Wk, (f16x4*)(Wh + 1048576), 262144);
        cvt_kernel<<<1024, 256, 0, stream>>>((const float4*)Wv, (f16x4*)(Wh + 2097152), 262144);
        concat_bias<<<12, 256, 0, stream>>>(bq, bk, bv, bqkv);

        gemm_bt<<<dim3(128, 24, 1), blk, 0, stream>>>(
            xh, Wh, bqkv, nullptr, qh, kh, vT,
            1024, 1024, 1024, 0, 3, 0, 0, 0);
        gemm_bt<<<dim3(16, 16, 8), blk, 0, stream>>>(
            qh, kh, nullptr, S, nullptr, nullptr, nullptr,
            1024, 1024, 1024, 2048, 2,
            (long)Nn_ * Dd, (long)Nn_ * Dd, (long)Nn_ * Nn_);
        softmax_rows<<<4096, 256, 0, stream>>>(S);
        gemm_bt<<<dim3(16, 8, 8), blk, 0, stream>>>(
            (const f16*)S, vT, nullptr, d_out, nullptr, nullptr, nullptr,
            2048, 4096, 2048, 1024, 2,
            (long)Nn_ * 4096, (long)Dd * Nn_, (long)Nn_ * Dd);
    } else {
        f16* xh  = wsh;
        f16* Wh  = wsh + 16777216;
        float* bqkv = (float*)(wsh + 19922944);
        f16* qh  = wsh + 19929088;
        f16* kh  = qh + 16777216;
        f16* vT  = kh + 16777216;
        float* S = (float*)(vT + 16777216);

        cvt_kernel<<<16384, 256, 0, stream>>>((const float4*)x, (f16x4*)xh, 4194304);
        cvt_kernel<<<1024, 256, 0, stream>>>((const float4*)Wq, (f16x4*)Wh, 262144);
        cvt_kernel<<<1024, 256, 0, stream>>>((const float4*)Wk, (f16x4*)(Wh + 1048576), 262144);
        cvt_kernel<<<1024, 256, 0, stream>>>((const float4*)Wv, (f16x4*)(Wh + 2097152), 262144);
        concat_bias<<<12, 256, 0, stream>>>(bq, bk, bv, bqkv);

        gemm_bt<<<dim3(128, 24, 1), blk, 0, stream>>>(
            xh, Wh, bqkv, nullptr, qh, kh, vT,
            1024, 1024, 1024, 0, 3, 0, 0, 0);

        for (int h = 0; h < 2; ++h) {
            const long b0 = 4L * h;
            gemm_bt<<<dim3(16, 16, 4), blk, 0, stream>>>(
                qh + b0 * Nn_ * Dd, kh + b0 * Nn_ * Dd, nullptr, S,
                nullptr, nullptr, nullptr,
                1024, 1024, 1024, 2048, 2,
                (long)Nn_ * Dd, (long)Nn_ * Dd, (long)Nn_ * Nn_);
            softmax_rows<<<2048, 256, 0, stream>>>(S);
            gemm_bt<<<dim3(16, 8, 4), blk, 0, stream>>>(
                (const f16*)S, vT + b0 * Dd * Nn_, nullptr,
                (float*)d_out + b0 * Nn_ * Dd, nullptr, nullptr, nullptr,
                2048, 4096, 2048, 1024, 2,
                (long)Nn_ * 4096, (long)Dd * Nn_, (long)Nn_ * Dd);
        }
    }
}